// Round 6
// baseline (256.270 us; speedup 1.0000x reference)
//
#include <hip/hip_runtime.h>

#define DIM_ 768
#define MID_ 96

typedef float f32x4 __attribute__((ext_vector_type(4)));
typedef __bf16 bf16x8 __attribute__((ext_vector_type(8)));
typedef __bf16 bf16x4 __attribute__((ext_vector_type(4)));

// ---------------------------------------------------------------------------
// K_prep: fused weight prep.
// Blocks [0,48): fold LN into down/down1 weights (192 waves -> (mat,n)).
// Blocks [48,141): bf16-cast up_w, pw_w; zero gvec partials.
// ---------------------------------------------------------------------------
__global__ __launch_bounds__(256) void k_prep(
        const float* __restrict__ dw, const float* __restrict__ db,
        const float* __restrict__ lnw0, const float* __restrict__ lnb0,
        const float* __restrict__ d1w, const float* __restrict__ d1b,
        const float* __restrict__ lnw1, const float* __restrict__ lnb1,
        __bf16* __restrict__ wln0, __bf16* __restrict__ wln1,
        float* __restrict__ swcb,
        const float* __restrict__ uw, const float* __restrict__ pw,
        __bf16* __restrict__ bup, __bf16* __restrict__ bpw,
        float* __restrict__ part) {
    if (blockIdx.x >= 48) {
        const int t = (blockIdx.x - 48) * 256 + threadIdx.x;
        const float* src;
        __bf16* dst;
        int i;
        if (t < 18432)      { src = uw; dst = bup; i = t; }
        else if (t < 23040) { src = pw; dst = bpw; i = t - 18432; }
        else if (t < 23808) { part[t - 23040] = 0.f; return; }
        else return;
        float4 v = reinterpret_cast<const float4*>(src)[i];
        bf16x4 o;
        o[0] = (__bf16)v.x; o[1] = (__bf16)v.y;
        o[2] = (__bf16)v.z; o[3] = (__bf16)v.w;
        *reinterpret_cast<bf16x4*>(dst + (size_t)i * 4) = o;
        return;
    }
    const int wid = blockIdx.x * 4 + (threadIdx.x >> 6);
    const int lane = threadIdx.x & 63;
    const int mat = wid >= 96;
    const int n = mat ? wid - 96 : wid;
    const float* W   = mat ? d1w : dw;
    const float* bia = mat ? d1b : db;
    const float* lw  = mat ? lnw1 : lnw0;
    const float* lb  = mat ? lnb1 : lnb0;
    __bf16* dst = mat ? wln1 : wln0;
    float sacc = 0.f, cacc = 0.f;
#pragma unroll
    for (int j = 0; j < 12; ++j) {
        const int k = j * 64 + lane;
        const float w = W[(size_t)n * DIM_ + k];
        const float val = w * lw[k];
        const __bf16 bv = (__bf16)val;
        dst[(size_t)n * DIM_ + k] = bv;
        sacc += (float)bv;
        cacc += lb[k] * w;
    }
#pragma unroll
    for (int m = 1; m < 64; m <<= 1) {
        sacc += __shfl_xor(sacc, m, 64);
        cacc += __shfl_xor(cacc, m, 64);
    }
    if (lane == 0) {
        swcb[mat * 192 + n] = sacc;               // sw
        swcb[mat * 192 + 96 + n] = cacc + bia[n]; // cb
    }
}

// ---------------------------------------------------------------------------
// K_downf: fused LN+GEMM for BOTH x and t in one dispatch.
// Grid 256: blocks [0,128) -> x, [128,256) -> t. Block: 1024 thr (16 waves),
// 256 rows; each wave owns 16 distinct rows x full N=96 (6 frags) --
// every x cache line requested once. W (96x768 bf16 = 147 KB) LDS-resident
// in fragment order (lane-contiguous ds_read_b128, conflict-free).
// 4-deep software-pipelined prefetch (8 named float4 regs, static unroll).
// LN algebraic: out = acc*rstd - mu*rstd*sw + cb (weights pre-folded).
// ---------------------------------------------------------------------------
__global__ __launch_bounds__(1024, 1) void k_downf(
        const float* __restrict__ xsrc, const float* __restrict__ tsrc,
        const __bf16* __restrict__ wln0, const __bf16* __restrict__ wln1,
        const float* __restrict__ swcb, __bf16* __restrict__ xemb,
        __bf16* __restrict__ temb, float* __restrict__ part) {
    extern __shared__ __bf16 Wp[];   // 96*768 = 73728 elems = 147456 B
    const int t = threadIdx.x;
    const int half = blockIdx.x >> 7;      // 0: x, 1: t
    const int mb = blockIdx.x & 127;
    const float* src = half ? tsrc : xsrc;
    const __bf16* wln = half ? wln1 : wln0;
    const float* sc = swcb + half * 192;
    __bf16* outb = half ? temb : xemb;

    // stage W in fragment order: idx = (kt*6 + f)*64 + lane
#pragma unroll
    for (int i = 0; i < 9; ++i) {
        const int idx = t + i * 1024;          // 0..9215
        const int ls = idx & 63;
        const int rem = idx >> 6;              // kt*6 + f
        const int kt = rem / 6;
        const int f = rem - kt * 6;
        const int row = f * 16 + (ls & 15);
        const int col = kt * 32 + (ls >> 4) * 8;
        *reinterpret_cast<bf16x8*>(Wp + (size_t)idx * 8) =
            *reinterpret_cast<const bf16x8*>(wln + (size_t)row * DIM_ + col);
    }
    __syncthreads();

    const int lane = t & 63, wave = t >> 6;   // 16 waves
    const int l15 = lane & 15, l4 = lane >> 4;
    const int row = mb * 256 + wave * 16 + l15;
    const float* rp = src + (size_t)row * DIM_ + l4 * 8;

    float s = 0.f, sq = 0.f;
    f32x4 acc[6] = {};

    float4 p0a = *reinterpret_cast<const float4*>(rp + 0);
    float4 p0b = *reinterpret_cast<const float4*>(rp + 4);
    float4 p1a = *reinterpret_cast<const float4*>(rp + 32);
    float4 p1b = *reinterpret_cast<const float4*>(rp + 36);
    float4 p2a = *reinterpret_cast<const float4*>(rp + 64);
    float4 p2b = *reinterpret_cast<const float4*>(rp + 68);
    float4 p3a = *reinterpret_cast<const float4*>(rp + 96);
    float4 p3b = *reinterpret_cast<const float4*>(rp + 100);

    auto consume = [&](float4& va, float4& vb, int kt) {
        const float4 v0 = va, v1 = vb;
        if (kt + 4 < 24) {   // static after unroll
            va = *reinterpret_cast<const float4*>(rp + (kt + 4) * 32);
            vb = *reinterpret_cast<const float4*>(rp + (kt + 4) * 32 + 4);
        }
        s += v0.x + v0.y + v0.z + v0.w + v1.x + v1.y + v1.z + v1.w;
        sq += v0.x * v0.x + v0.y * v0.y + v0.z * v0.z + v0.w * v0.w +
              v1.x * v1.x + v1.y * v1.y + v1.z * v1.z + v1.w * v1.w;
        bf16x8 a;
        a[0] = (__bf16)v0.x; a[1] = (__bf16)v0.y;
        a[2] = (__bf16)v0.z; a[3] = (__bf16)v0.w;
        a[4] = (__bf16)v1.x; a[5] = (__bf16)v1.y;
        a[6] = (__bf16)v1.z; a[7] = (__bf16)v1.w;
        const __bf16* bp = Wp + ((size_t)(kt * 6) * 64 + lane) * 8;
#pragma unroll
        for (int f = 0; f < 6; ++f) {
            bf16x8 b = *reinterpret_cast<const bf16x8*>(bp + (size_t)f * 64 * 8);
            acc[f] = __builtin_amdgcn_mfma_f32_16x16x32_bf16(a, b, acc[f], 0, 0, 0);
        }
    };

#pragma unroll
    for (int kb = 0; kb < 24; kb += 4) {
        consume(p0a, p0b, kb + 0);
        consume(p1a, p1b, kb + 1);
        consume(p2a, p2b, kb + 2);
        consume(p3a, p3b, kb + 3);
    }

    // finish stats: combine the 4 k-quarter lanes of each row
    s += __shfl_xor(s, 16, 64); sq += __shfl_xor(sq, 16, 64);
    s += __shfl_xor(s, 32, 64); sq += __shfl_xor(sq, 32, 64);
    const float mean = s * (1.f / 768.f);
    const float rstd = rsqrtf(sq * (1.f / 768.f) - mean * mean + 1e-6f);
    const float mur = mean * rstd;
    float rstd_r[4], mur_r[4];
#pragma unroll
    for (int rr = 0; rr < 4; ++rr) {
        rstd_r[rr] = __shfl(rstd, l4 * 4 + rr, 64);
        mur_r[rr]  = __shfl(mur,  l4 * 4 + rr, 64);
    }

    const int orow0 = mb * 256 + wave * 16 + l4 * 4;
    const int batch = mb >> 4;     // 16 blocks per image
#pragma unroll
    for (int f = 0; f < 6; ++f) {
        const int col = f * 16 + l15;
        const float swc = sc[col];
        const float cbc = sc[96 + col];
        float colsum = 0.f;
#pragma unroll
        for (int rr = 0; rr < 4; ++rr) {
            const float val = acc[f][rr] * rstd_r[rr] - mur_r[rr] * swc + cbc;
            outb[(size_t)(orow0 + rr) * MID_ + col] = (__bf16)val;
            colsum += val;
        }
        if (half == 0) {
            colsum += __shfl_xor(colsum, 16, 64);
            colsum += __shfl_xor(colsum, 32, 64);
            if (l4 == 0) atomicAdd(&part[batch * MID_ + col], colsum);
        }
    }
}

// ---------------------------------------------------------------------------
// K_mlp: gvec mean from part, MLP (96->24 relu ->4), softmax -> wts [8,4]
// ---------------------------------------------------------------------------
__global__ __launch_bounds__(128) void k_mlp(const float* __restrict__ part,
        const float* __restrict__ m1w, const float* __restrict__ m1b,
        const float* __restrict__ m2w, const float* __restrict__ m2b,
        float* __restrict__ wts) {
    const int b = blockIdx.x, t = threadIdx.x;
    __shared__ float gv[96];
    __shared__ float hid[24];
    __shared__ float lg[4];
    if (t < 96) gv[t] = part[b * MID_ + t] * (1.f / 4096.f);
    __syncthreads();
    if (t < 24) {
        float s = m1b[t];
        for (int c = 0; c < 96; ++c) s += gv[c] * m1w[t * 96 + c];
        hid[t] = fmaxf(s, 0.f);
    }
    __syncthreads();
    if (t < 4) {
        float s = m2b[t];
        for (int j = 0; j < 24; ++j) s += hid[j] * m2w[t * 24 + j];
        lg[t] = s;
    }
    __syncthreads();
    if (t < 4) {
        const float m = fmaxf(fmaxf(lg[0], lg[1]), fmaxf(lg[2], lg[3]));
        const float e = __expf(lg[t] - m);
        const float sum = __expf(lg[0] - m) + __expf(lg[1] - m) +
                          __expf(lg[2] - m) + __expf(lg[3] - m);
        wts[b * 4 + t] = e / sum;
    }
}

// ---------------------------------------------------------------------------
// K_dwconv: depthwise 3x3 conv (zero pad) + SiLU. temb bf16 -> y bf16.
// ---------------------------------------------------------------------------
__global__ __launch_bounds__(256) void k_dwconv(const __bf16* __restrict__ temb,
        const float* __restrict__ dww, const float* __restrict__ dwb,
        __bf16* __restrict__ y) {
    __shared__ float wls[96 * 9];
    __shared__ float bls[96];
    const int t = threadIdx.x;
    for (int i = t; i < 96 * 9; i += 256) wls[i] = dww[i];
    if (t < 96) bls[t] = dwb[t];
    __syncthreads();
    const int b = blockIdx.x >> 6, h = blockIdx.x & 63;
    const __bf16* base = temb + (size_t)b * 4096 * MID_;
    for (int o = t; o < 64 * 96; o += 256) {
        const int w = o / 96;
        const int c = o - w * 96;
        float acc = bls[c];
#pragma unroll
        for (int dh = 0; dh < 3; ++dh) {
            const int hh = h + dh - 1;
            if (hh < 0 || hh > 63) continue;
#pragma unroll
            for (int dw = 0; dw < 3; ++dw) {
                const int ww = w + dw - 1;
                if (ww < 0 || ww > 63) continue;
                acc += (float)base[((size_t)hh * 64 + ww) * MID_ + c] *
                       wls[c * 9 + dh * 3 + dw];
            }
        }
        y[((size_t)(b * 64 + h) * 64 + w) * MID_ + c] =
            (__bf16)(acc / (1.f + __expf(-acc)));
    }
}

// ---------------------------------------------------------------------------
// K_style: style GEMM (y @ pw_w^T + pw_b) fused with modulation:
// common = x_emb * (1 + gamma) + beta -> bf16. K=96 fully staged, 1 barrier.
// ---------------------------------------------------------------------------
__global__ __launch_bounds__(256) void k_style(const __bf16* __restrict__ y,
        const __bf16* __restrict__ wpw, const float* __restrict__ pwb,
        const __bf16* __restrict__ xemb, __bf16* __restrict__ common) {
    __shared__ bf16x8 As[64][13];
    __shared__ bf16x8 Bs[192][13];
    const int t = threadIdx.x;
    const int row0 = blockIdx.x * 64;
    for (int idx = t; idx < 768; idx += 256) {
        const int rr = idx / 12, q = idx - rr * 12;
        As[rr][q] = *reinterpret_cast<const bf16x8*>(
            y + (size_t)(row0 + rr) * MID_ + q * 8);
    }
    for (int idx = t; idx < 2304; idx += 256) {
        const int rr = idx / 12, q = idx - rr * 12;
        Bs[rr][q] = *reinterpret_cast<const bf16x8*>(
            wpw + (size_t)rr * MID_ + q * 8);
    }
    __syncthreads();
    const int lane = t & 63, wave = t >> 6;
    const int l15 = lane & 15, l4 = lane >> 4;
    f32x4 acc[12] = {};
    const int ar = wave * 16 + l15;
#pragma unroll
    for (int kt = 0; kt < 3; ++kt) {
        bf16x8 a = As[ar][kt * 4 + l4];
#pragma unroll
        for (int f = 0; f < 12; ++f) {
            bf16x8 b = Bs[f * 16 + l15][kt * 4 + l4];
            acc[f] = __builtin_amdgcn_mfma_f32_16x16x32_bf16(a, b, acc[f], 0, 0, 0);
        }
    }
    const int orow = row0 + wave * 16 + l4 * 4;
#pragma unroll
    for (int f = 0; f < 6; ++f) {
        const int col = f * 16 + l15;
        const float pbg = pwb[col];
        const float pbb = pwb[col + 96];
#pragma unroll
        for (int rr = 0; rr < 4; ++rr) {
            const float g = acc[f][rr] + pbg;
            const float bt = acc[f + 6][rr] + pbb;
            const float xe = (float)xemb[(size_t)(orow + rr) * MID_ + col];
            common[(size_t)(orow + rr) * MID_ + col] = (__bf16)(xe * (1.f + g) + bt);
        }
    }
}

// ---------------------------------------------------------------------------
// K_circ: circular 7x7 conv (== rfft2/irfft2 product). dyn built in LDS.
// ---------------------------------------------------------------------------
__global__ __launch_bounds__(192) void k_circ(const __bf16* __restrict__ common,
        const float* __restrict__ wts, const float* __restrict__ basis,
        __bf16* __restrict__ outc) {
    __shared__ float dyn[49][96];
    const int t = threadIdx.x;
    const int b = blockIdx.x >> 7;
    const int h = (blockIdx.x >> 1) & 63;
    const int wslice = blockIdx.x & 1;
    const float w0 = wts[b * 4 + 0], w1 = wts[b * 4 + 1];
    const float w2 = wts[b * 4 + 2], w3 = wts[b * 4 + 3];
    for (int idx = t; idx < 4704; idx += 192) {
        const int c = idx / 49;
        const int pq = idx - c * 49;
        const size_t off = (size_t)c * 49 + pq;
        dyn[pq][c] = w0 * basis[off] + w1 * basis[off + 4704] +
                     w2 * basis[off + 9408] + w3 * basis[off + 14112];
    }
    __syncthreads();
    const int c = t % 96;
    const int wg = t / 96;
    const int wbase = wslice * 32 + wg * 16;
    const __bf16* cb = common + (size_t)b * 4096 * MID_ + c;
    float acc[16] = {};
#pragma unroll 1
    for (int p = 0; p < 7; ++p) {
        const int hh = (h + 3 - p) & 63;
        const __bf16* rp = cb + (size_t)hh * 64 * MID_;
        float dynr[7];
#pragma unroll
        for (int q = 0; q < 7; ++q) dynr[q] = dyn[p * 7 + q][c];
#pragma unroll
        for (int i = 0; i < 22; ++i) {
            const int ww = (wbase - 3 + i) & 63;
            const float cm = (float)rp[(size_t)ww * MID_];
#pragma unroll
            for (int q = 0; q < 7; ++q) {
                const int li = i + q - 6;
                if (li >= 0 && li < 16) acc[li] += dynr[q] * cm;
            }
        }
    }
    const size_t obase = ((size_t)(b * 64 + h) * 64 + wbase) * MID_ + c;
#pragma unroll
    for (int li = 0; li < 16; ++li)
        outc[obase + (size_t)li * MID_] = (__bf16)acc[li];
}

// ---------------------------------------------------------------------------
// K_up: out = a_in[32768,96] @ up_w_bf16[768,96]^T + up_b + x  (fp32 out)
// ---------------------------------------------------------------------------
__global__ __launch_bounds__(256) void k_up(const __bf16* __restrict__ a_in,
        const __bf16* __restrict__ wbf, const float* __restrict__ upb,
        const float* __restrict__ x, float* __restrict__ out) {
    __shared__ bf16x8 As[128][13];
    __shared__ bf16x8 Ws[96][13];
    const int t = threadIdx.x;
    const int mt = blockIdx.x >> 3, nt = blockIdx.x & 7;
    const int row0 = mt * 128, col0 = nt * 96;
    for (int idx = t; idx < 1536; idx += 256) {
        const int rr = idx / 12, q = idx - rr * 12;
        As[rr][q] = *reinterpret_cast<const bf16x8*>(
            a_in + (size_t)(row0 + rr) * MID_ + q * 8);
    }
    for (int idx = t; idx < 1152; idx += 256) {
        const int rr = idx / 12, q = idx - rr * 12;
        Ws[rr][q] = *reinterpret_cast<const bf16x8*>(
            wbf + (size_t)(col0 + rr) * MID_ + q * 8);
    }
    __syncthreads();
    const int lane = t & 63, wave = t >> 6;
    const int l15 = lane & 15, l4 = lane >> 4;
    f32x4 acc[2][6] = {};
#pragma unroll
    for (int kt = 0; kt < 3; ++kt) {
        bf16x8 a0 = As[wave * 32 + l15][kt * 4 + l4];
        bf16x8 a1 = As[wave * 32 + 16 + l15][kt * 4 + l4];
#pragma unroll
        for (int f = 0; f < 6; ++f) {
            bf16x8 b = Ws[f * 16 + l15][kt * 4 + l4];
            acc[0][f] = __builtin_amdgcn_mfma_f32_16x16x32_bf16(a0, b, acc[0][f], 0, 0, 0);
            acc[1][f] = __builtin_amdgcn_mfma_f32_16x16x32_bf16(a1, b, acc[1][f], 0, 0, 0);
        }
    }
#pragma unroll
    for (int mr = 0; mr < 2; ++mr) {
        const int orow = row0 + wave * 32 + mr * 16 + l4 * 4;
#pragma unroll
        for (int f = 0; f < 6; ++f) {
            const int col = col0 + f * 16 + l15;
            const float ub = upb[col];
#pragma unroll
            for (int rr = 0; rr < 4; ++rr) {
                const size_t idx = (size_t)(orow + rr) * DIM_ + col;
                out[idx] = acc[mr][f][rr] + ub + x[idx];
            }
        }
    }
}

// ---------------------------------------------------------------------------
extern "C" void kernel_launch(void* const* d_in, const int* in_sizes, int n_in,
                              void* d_out, int out_size, void* d_ws, size_t ws_size,
                              hipStream_t stream) {
    (void)in_sizes; (void)n_in; (void)out_size; (void)ws_size;
    const float* x      = (const float*)d_in[0];
    const float* tt     = (const float*)d_in[1];
    const float* ln_w   = (const float*)d_in[2];
    const float* ln_b   = (const float*)d_in[3];
    const float* down_w = (const float*)d_in[4];
    const float* down_b = (const float*)d_in[5];
    const float* ln1_w  = (const float*)d_in[6];
    const float* ln1_b  = (const float*)d_in[7];
    const float* down1_w= (const float*)d_in[8];
    const float* down1_b= (const float*)d_in[9];
    const float* dw_w   = (const float*)d_in[10];
    const float* dw_b   = (const float*)d_in[11];
    const float* pw_w   = (const float*)d_in[12];
    const float* pw_b   = (const float*)d_in[13];
    const float* m1w    = (const float*)d_in[14];
    const float* m1b    = (const float*)d_in[15];
    const float* m2w    = (const float*)d_in[16];
    const float* m2b    = (const float*)d_in[17];
    const float* basis  = (const float*)d_in[18];
    const float* up_w   = (const float*)d_in[19];
    const float* up_b   = (const float*)d_in[20];
    float* out = (float*)d_out;
    char* ws = (char*)d_ws;

    // workspace layout (bytes)
    __bf16* wln_down  = (__bf16*)(ws + 0);          // 96*768*2  = 147456
    __bf16* wln_down1 = (__bf16*)(ws + 147456);
    __bf16* wbf_up    = (__bf16*)(ws + 294912);     // 768*96*2
    __bf16* wbf_pw    = (__bf16*)(ws + 442368);     // 192*96*2 = 36864
    float*  part      = (float*)(ws + 479232);      // 8*96*4 = 3072
    float*  wts       = (float*)(ws + 482304);      // 32*4
    float*  swcb      = (float*)(ws + 482560);      // 2*192*4 = 1536
    __bf16* x_emb     = (__bf16*)(ws + 524288);     // 32768*96*2 = 6291456
    __bf16* t_emb     = (__bf16*)(ws + 6815744);
    __bf16* ybuf      = (__bf16*)(ws + 13107200);
    __bf16* common    = (__bf16*)(ws + 19398656);
    __bf16* convout   = (__bf16*)(ws + 25690112);

    // opt-in to >64KB dynamic LDS for k_downf (not a stream op; capture-safe)
    (void)hipFuncSetAttribute((const void*)k_downf,
                              hipFuncAttributeMaxDynamicSharedMemorySize, 147456);

    k_prep<<<141, 256, 0, stream>>>(down_w, down_b, ln_w, ln_b,
                                    down1_w, down1_b, ln1_w, ln1_b,
                                    wln_down, wln_down1, swcb,
                                    up_w, pw_w, wbf_up, wbf_pw, part);
    k_downf<<<256, 1024, 147456, stream>>>(x, tt, wln_down, wln_down1, swcb,
                                           x_emb, t_emb, part);
    k_mlp<<<8, 128, 0, stream>>>(part, m1w, m1b, m2w, m2b, wts);
    k_dwconv<<<512, 256, 0, stream>>>(t_emb, dw_w, dw_b, ybuf);
    k_style<<<512, 256, 0, stream>>>(ybuf, wbf_pw, pw_b, x_emb, common);
    k_circ<<<1024, 192, 0, stream>>>(common, wts, basis, convout);
    k_up<<<2048, 256, 0, stream>>>(convout, wbf_up, up_b, x, out);
}

// Round 7
// 177.874 us; speedup vs baseline: 1.4407x; 1.4407x over previous
//
#include <hip/hip_runtime.h>

#define DIM_ 768
#define MID_ 96

typedef float f32x4 __attribute__((ext_vector_type(4)));
typedef __bf16 bf16x8 __attribute__((ext_vector_type(8)));
typedef __bf16 bf16x4 __attribute__((ext_vector_type(4)));

// ---------------------------------------------------------------------------
// K_prep: fused weight prep.
// Blocks [0,48): fold LN into down/down1 weights (192 waves -> (mat,n)).
// Blocks [48,141): bf16-cast up_w, pw_w; zero gvec partials.
// ---------------------------------------------------------------------------
__global__ __launch_bounds__(256) void k_prep(
        const float* __restrict__ dw, const float* __restrict__ db,
        const float* __restrict__ lnw0, const float* __restrict__ lnb0,
        const float* __restrict__ d1w, const float* __restrict__ d1b,
        const float* __restrict__ lnw1, const float* __restrict__ lnb1,
        __bf16* __restrict__ wln0, __bf16* __restrict__ wln1,
        float* __restrict__ swcb,
        const float* __restrict__ uw, const float* __restrict__ pw,
        __bf16* __restrict__ bup, __bf16* __restrict__ bpw,
        float* __restrict__ part) {
    if (blockIdx.x >= 48) {
        const int t = (blockIdx.x - 48) * 256 + threadIdx.x;
        const float* src;
        __bf16* dst;
        int i;
        if (t < 18432)      { src = uw; dst = bup; i = t; }
        else if (t < 23040) { src = pw; dst = bpw; i = t - 18432; }
        else if (t < 23808) { part[t - 23040] = 0.f; return; }
        else return;
        float4 v = reinterpret_cast<const float4*>(src)[i];
        bf16x4 o;
        o[0] = (__bf16)v.x; o[1] = (__bf16)v.y;
        o[2] = (__bf16)v.z; o[3] = (__bf16)v.w;
        *reinterpret_cast<bf16x4*>(dst + (size_t)i * 4) = o;
        return;
    }
    const int wid = blockIdx.x * 4 + (threadIdx.x >> 6);
    const int lane = threadIdx.x & 63;
    const int mat = wid >= 96;
    const int n = mat ? wid - 96 : wid;
    const float* W   = mat ? d1w : dw;
    const float* bia = mat ? d1b : db;
    const float* lw  = mat ? lnw1 : lnw0;
    const float* lb  = mat ? lnb1 : lnb0;
    __bf16* dst = mat ? wln1 : wln0;
    float sacc = 0.f, cacc = 0.f;
#pragma unroll
    for (int j = 0; j < 12; ++j) {
        const int k = j * 64 + lane;
        const float w = W[(size_t)n * DIM_ + k];
        const float val = w * lw[k];
        const __bf16 bv = (__bf16)val;
        dst[(size_t)n * DIM_ + k] = bv;
        sacc += (float)bv;
        cacc += lb[k] * w;
    }
#pragma unroll
    for (int m = 1; m < 64; m <<= 1) {
        sacc += __shfl_xor(sacc, m, 64);
        cacc += __shfl_xor(cacc, m, 64);
    }
    if (lane == 0) {
        swcb[mat * 192 + n] = sacc;               // sw
        swcb[mat * 192 + 96 + n] = cacc + bia[n]; // cb
    }
}

// ---------------------------------------------------------------------------
// K_downf: fused LN+GEMM for BOTH x and t in one dispatch.
// Grid 256: blocks [0,128) -> x, [128,256) -> t. Block: 1024 thr (16 waves),
// 256 rows; each wave owns 16 distinct rows x full N=96 (6 frags).
// W (96x768 bf16 = 147 KB) LDS-resident in fragment order (conflict-free).
// 4-deep software-pipelined prefetch (8 named float4 regs, static unroll).
// amdgpu_waves_per_eu(4,4): dynamic LDS hides occupancy from the allocator;
// without this it targets 8 waves/EU (64 VGPR) and SPILLS (r6: 165MB writes).
// LN algebraic: out = acc*rstd - mu*rstd*sw + cb (weights pre-folded).
// ---------------------------------------------------------------------------
__global__ __launch_bounds__(1024)
__attribute__((amdgpu_waves_per_eu(4, 4)))
void k_downf(
        const float* __restrict__ xsrc, const float* __restrict__ tsrc,
        const __bf16* __restrict__ wln0, const __bf16* __restrict__ wln1,
        const float* __restrict__ swcb, __bf16* __restrict__ xemb,
        __bf16* __restrict__ temb, float* __restrict__ part) {
    extern __shared__ __bf16 Wp[];   // 96*768 = 73728 elems = 147456 B
    const int t = threadIdx.x;
    const int half = blockIdx.x >> 7;      // 0: x, 1: t
    const int mb = blockIdx.x & 127;
    const float* src = half ? tsrc : xsrc;
    const __bf16* wln = half ? wln1 : wln0;
    const float* sc = swcb + half * 192;
    __bf16* outb = half ? temb : xemb;

    // stage W in fragment order: idx = (kt*6 + f)*64 + lane
#pragma unroll
    for (int i = 0; i < 9; ++i) {
        const int idx = t + i * 1024;          // 0..9215
        const int ls = idx & 63;
        const int rem = idx >> 6;              // kt*6 + f
        const int kt = rem / 6;
        const int f = rem - kt * 6;
        const int row = f * 16 + (ls & 15);
        const int col = kt * 32 + (ls >> 4) * 8;
        *reinterpret_cast<bf16x8*>(Wp + (size_t)idx * 8) =
            *reinterpret_cast<const bf16x8*>(wln + (size_t)row * DIM_ + col);
    }
    __syncthreads();

    const int lane = t & 63, wave = t >> 6;   // 16 waves
    const int l15 = lane & 15, l4 = lane >> 4;
    const int row = mb * 256 + wave * 16 + l15;
    const float* rp = src + (size_t)row * DIM_ + l4 * 8;

    float s = 0.f, sq = 0.f;
    f32x4 acc[6] = {};

    float4 p0a = *reinterpret_cast<const float4*>(rp + 0);
    float4 p0b = *reinterpret_cast<const float4*>(rp + 4);
    float4 p1a = *reinterpret_cast<const float4*>(rp + 32);
    float4 p1b = *reinterpret_cast<const float4*>(rp + 36);
    float4 p2a = *reinterpret_cast<const float4*>(rp + 64);
    float4 p2b = *reinterpret_cast<const float4*>(rp + 68);
    float4 p3a = *reinterpret_cast<const float4*>(rp + 96);
    float4 p3b = *reinterpret_cast<const float4*>(rp + 100);

    auto consume = [&](float4& va, float4& vb, int kt) {
        const float4 v0 = va, v1 = vb;
        if (kt + 4 < 24) {   // static after unroll
            va = *reinterpret_cast<const float4*>(rp + (kt + 4) * 32);
            vb = *reinterpret_cast<const float4*>(rp + (kt + 4) * 32 + 4);
        }
        s += v0.x + v0.y + v0.z + v0.w + v1.x + v1.y + v1.z + v1.w;
        sq += v0.x * v0.x + v0.y * v0.y + v0.z * v0.z + v0.w * v0.w +
              v1.x * v1.x + v1.y * v1.y + v1.z * v1.z + v1.w * v1.w;
        bf16x8 a;
        a[0] = (__bf16)v0.x; a[1] = (__bf16)v0.y;
        a[2] = (__bf16)v0.z; a[3] = (__bf16)v0.w;
        a[4] = (__bf16)v1.x; a[5] = (__bf16)v1.y;
        a[6] = (__bf16)v1.z; a[7] = (__bf16)v1.w;
        const __bf16* bp = Wp + ((size_t)(kt * 6) * 64 + lane) * 8;
#pragma unroll
        for (int f = 0; f < 6; ++f) {
            bf16x8 b = *reinterpret_cast<const bf16x8*>(bp + (size_t)f * 64 * 8);
            acc[f] = __builtin_amdgcn_mfma_f32_16x16x32_bf16(a, b, acc[f], 0, 0, 0);
        }
    };

#pragma unroll
    for (int kb = 0; kb < 24; kb += 4) {
        consume(p0a, p0b, kb + 0);
        consume(p1a, p1b, kb + 1);
        consume(p2a, p2b, kb + 2);
        consume(p3a, p3b, kb + 3);
    }

    // finish stats: combine the 4 k-quarter lanes of each row
    s += __shfl_xor(s, 16, 64); sq += __shfl_xor(sq, 16, 64);
    s += __shfl_xor(s, 32, 64); sq += __shfl_xor(sq, 32, 64);
    const float mean = s * (1.f / 768.f);
    const float rstd = rsqrtf(sq * (1.f / 768.f) - mean * mean + 1e-6f);
    const float mur = mean * rstd;
    float rstd_r[4], mur_r[4];
#pragma unroll
    for (int rr = 0; rr < 4; ++rr) {
        rstd_r[rr] = __shfl(rstd, l4 * 4 + rr, 64);
        mur_r[rr]  = __shfl(mur,  l4 * 4 + rr, 64);
    }

    const int orow0 = mb * 256 + wave * 16 + l4 * 4;
    const int batch = mb >> 4;     // 16 blocks per image
#pragma unroll
    for (int f = 0; f < 6; ++f) {
        const int col = f * 16 + l15;
        const float swc = sc[col];
        const float cbc = sc[96 + col];
        float colsum = 0.f;
#pragma unroll
        for (int rr = 0; rr < 4; ++rr) {
            const float val = acc[f][rr] * rstd_r[rr] - mur_r[rr] * swc + cbc;
            outb[(size_t)(orow0 + rr) * MID_ + col] = (__bf16)val;
            colsum += val;
        }
        if (half == 0) {
            colsum += __shfl_xor(colsum, 16, 64);
            colsum += __shfl_xor(colsum, 32, 64);
            if (l4 == 0) atomicAdd(&part[batch * MID_ + col], colsum);
        }
    }
}

// ---------------------------------------------------------------------------
// K_mlp: gvec mean from part, MLP (96->24 relu ->4), softmax -> wts [8,4]
// ---------------------------------------------------------------------------
__global__ __launch_bounds__(128) void k_mlp(const float* __restrict__ part,
        const float* __restrict__ m1w, const float* __restrict__ m1b,
        const float* __restrict__ m2w, const float* __restrict__ m2b,
        float* __restrict__ wts) {
    const int b = blockIdx.x, t = threadIdx.x;
    __shared__ float gv[96];
    __shared__ float hid[24];
    __shared__ float lg[4];
    if (t < 96) gv[t] = part[b * MID_ + t] * (1.f / 4096.f);
    __syncthreads();
    if (t < 24) {
        float s = m1b[t];
        for (int c = 0; c < 96; ++c) s += gv[c] * m1w[t * 96 + c];
        hid[t] = fmaxf(s, 0.f);
    }
    __syncthreads();
    if (t < 4) {
        float s = m2b[t];
        for (int j = 0; j < 24; ++j) s += hid[j] * m2w[t * 24 + j];
        lg[t] = s;
    }
    __syncthreads();
    if (t < 4) {
        const float m = fmaxf(fmaxf(lg[0], lg[1]), fmaxf(lg[2], lg[3]));
        const float e = __expf(lg[t] - m);
        const float sum = __expf(lg[0] - m) + __expf(lg[1] - m) +
                          __expf(lg[2] - m) + __expf(lg[3] - m);
        wts[b * 4 + t] = e / sum;
    }
}

// ---------------------------------------------------------------------------
// K_dwconv: depthwise 3x3 conv (zero pad) + SiLU. temb bf16 -> y bf16.
// ---------------------------------------------------------------------------
__global__ __launch_bounds__(256) void k_dwconv(const __bf16* __restrict__ temb,
        const float* __restrict__ dww, const float* __restrict__ dwb,
        __bf16* __restrict__ y) {
    __shared__ float wls[96 * 9];
    __shared__ float bls[96];
    const int t = threadIdx.x;
    for (int i = t; i < 96 * 9; i += 256) wls[i] = dww[i];
    if (t < 96) bls[t] = dwb[t];
    __syncthreads();
    const int b = blockIdx.x >> 6, h = blockIdx.x & 63;
    const __bf16* base = temb + (size_t)b * 4096 * MID_;
    for (int o = t; o < 64 * 96; o += 256) {
        const int w = o / 96;
        const int c = o - w * 96;
        float acc = bls[c];
#pragma unroll
        for (int dh = 0; dh < 3; ++dh) {
            const int hh = h + dh - 1;
            if (hh < 0 || hh > 63) continue;
#pragma unroll
            for (int dw = 0; dw < 3; ++dw) {
                const int ww = w + dw - 1;
                if (ww < 0 || ww > 63) continue;
                acc += (float)base[((size_t)hh * 64 + ww) * MID_ + c] *
                       wls[c * 9 + dh * 3 + dw];
            }
        }
        y[((size_t)(b * 64 + h) * 64 + w) * MID_ + c] =
            (__bf16)(acc / (1.f + __expf(-acc)));
    }
}

// ---------------------------------------------------------------------------
// K_style: style GEMM (y @ pw_w^T + pw_b) fused with modulation:
// common = x_emb * (1 + gamma) + beta -> bf16. K=96 fully staged, 1 barrier.
// ---------------------------------------------------------------------------
__global__ __launch_bounds__(256) void k_style(const __bf16* __restrict__ y,
        const __bf16* __restrict__ wpw, const float* __restrict__ pwb,
        const __bf16* __restrict__ xemb, __bf16* __restrict__ common) {
    __shared__ bf16x8 As[64][13];
    __shared__ bf16x8 Bs[192][13];
    const int t = threadIdx.x;
    const int row0 = blockIdx.x * 64;
    for (int idx = t; idx < 768; idx += 256) {
        const int rr = idx / 12, q = idx - rr * 12;
        As[rr][q] = *reinterpret_cast<const bf16x8*>(
            y + (size_t)(row0 + rr) * MID_ + q * 8);
    }
    for (int idx = t; idx < 2304; idx += 256) {
        const int rr = idx / 12, q = idx - rr * 12;
        Bs[rr][q] = *reinterpret_cast<const bf16x8*>(
            wpw + (size_t)rr * MID_ + q * 8);
    }
    __syncthreads();
    const int lane = t & 63, wave = t >> 6;
    const int l15 = lane & 15, l4 = lane >> 4;
    f32x4 acc[12] = {};
    const int ar = wave * 16 + l15;
#pragma unroll
    for (int kt = 0; kt < 3; ++kt) {
        bf16x8 a = As[ar][kt * 4 + l4];
#pragma unroll
        for (int f = 0; f < 12; ++f) {
            bf16x8 b = Bs[f * 16 + l15][kt * 4 + l4];
            acc[f] = __builtin_amdgcn_mfma_f32_16x16x32_bf16(a, b, acc[f], 0, 0, 0);
        }
    }
    const int orow = row0 + wave * 16 + l4 * 4;
#pragma unroll
    for (int f = 0; f < 6; ++f) {
        const int col = f * 16 + l15;
        const float pbg = pwb[col];
        const float pbb = pwb[col + 96];
#pragma unroll
        for (int rr = 0; rr < 4; ++rr) {
            const float g = acc[f][rr] + pbg;
            const float bt = acc[f + 6][rr] + pbb;
            const float xe = (float)xemb[(size_t)(orow + rr) * MID_ + col];
            common[(size_t)(orow + rr) * MID_ + col] = (__bf16)(xe * (1.f + g) + bt);
        }
    }
}

// ---------------------------------------------------------------------------
// K_circ: circular 7x7 conv (== rfft2/irfft2 product). dyn built in LDS.
// ---------------------------------------------------------------------------
__global__ __launch_bounds__(192) void k_circ(const __bf16* __restrict__ common,
        const float* __restrict__ wts, const float* __restrict__ basis,
        __bf16* __restrict__ outc) {
    __shared__ float dyn[49][96];
    const int t = threadIdx.x;
    const int b = blockIdx.x >> 7;
    const int h = (blockIdx.x >> 1) & 63;
    const int wslice = blockIdx.x & 1;
    const float w0 = wts[b * 4 + 0], w1 = wts[b * 4 + 1];
    const float w2 = wts[b * 4 + 2], w3 = wts[b * 4 + 3];
    for (int idx = t; idx < 4704; idx += 192) {
        const int c = idx / 49;
        const int pq = idx - c * 49;
        const size_t off = (size_t)c * 49 + pq;
        dyn[pq][c] = w0 * basis[off] + w1 * basis[off + 4704] +
                     w2 * basis[off + 9408] + w3 * basis[off + 14112];
    }
    __syncthreads();
    const int c = t % 96;
    const int wg = t / 96;
    const int wbase = wslice * 32 + wg * 16;
    const __bf16* cb = common + (size_t)b * 4096 * MID_ + c;
    float acc[16] = {};
#pragma unroll 1
    for (int p = 0; p < 7; ++p) {
        const int hh = (h + 3 - p) & 63;
        const __bf16* rp = cb + (size_t)hh * 64 * MID_;
        float dynr[7];
#pragma unroll
        for (int q = 0; q < 7; ++q) dynr[q] = dyn[p * 7 + q][c];
#pragma unroll
        for (int i = 0; i < 22; ++i) {
            const int ww = (wbase - 3 + i) & 63;
            const float cm = (float)rp[(size_t)ww * MID_];
#pragma unroll
            for (int q = 0; q < 7; ++q) {
                const int li = i + q - 6;
                if (li >= 0 && li < 16) acc[li] += dynr[q] * cm;
            }
        }
    }
    const size_t obase = ((size_t)(b * 64 + h) * 64 + wbase) * MID_ + c;
#pragma unroll
    for (int li = 0; li < 16; ++li)
        outc[obase + (size_t)li * MID_] = (__bf16)acc[li];
}

// ---------------------------------------------------------------------------
// K_up: out = a_in[32768,96] @ up_w_bf16[768,96]^T + up_b + x  (fp32 out)
// ---------------------------------------------------------------------------
__global__ __launch_bounds__(256) void k_up(const __bf16* __restrict__ a_in,
        const __bf16* __restrict__ wbf, const float* __restrict__ upb,
        const float* __restrict__ x, float* __restrict__ out) {
    __shared__ bf16x8 As[128][13];
    __shared__ bf16x8 Ws[96][13];
    const int t = threadIdx.x;
    const int mt = blockIdx.x >> 3, nt = blockIdx.x & 7;
    const int row0 = mt * 128, col0 = nt * 96;
    for (int idx = t; idx < 1536; idx += 256) {
        const int rr = idx / 12, q = idx - rr * 12;
        As[rr][q] = *reinterpret_cast<const bf16x8*>(
            a_in + (size_t)(row0 + rr) * MID_ + q * 8);
    }
    for (int idx = t; idx < 1152; idx += 256) {
        const int rr = idx / 12, q = idx - rr * 12;
        Ws[rr][q] = *reinterpret_cast<const bf16x8*>(
            wbf + (size_t)(col0 + rr) * MID_ + q * 8);
    }
    __syncthreads();
    const int lane = t & 63, wave = t >> 6;
    const int l15 = lane & 15, l4 = lane >> 4;
    f32x4 acc[2][6] = {};
#pragma unroll
    for (int kt = 0; kt < 3; ++kt) {
        bf16x8 a0 = As[wave * 32 + l15][kt * 4 + l4];
        bf16x8 a1 = As[wave * 32 + 16 + l15][kt * 4 + l4];
#pragma unroll
        for (int f = 0; f < 6; ++f) {
            bf16x8 b = Ws[f * 16 + l15][kt * 4 + l4];
            acc[0][f] = __builtin_amdgcn_mfma_f32_16x16x32_bf16(a0, b, acc[0][f], 0, 0, 0);
            acc[1][f] = __builtin_amdgcn_mfma_f32_16x16x32_bf16(a1, b, acc[1][f], 0, 0, 0);
        }
    }
#pragma unroll
    for (int mr = 0; mr < 2; ++mr) {
        const int orow = row0 + wave * 32 + mr * 16 + l4 * 4;
#pragma unroll
        for (int f = 0; f < 6; ++f) {
            const int col = col0 + f * 16 + l15;
            const float ub = upb[col];
#pragma unroll
            for (int rr = 0; rr < 4; ++rr) {
                const size_t idx = (size_t)(orow + rr) * DIM_ + col;
                out[idx] = acc[mr][f][rr] + ub + x[idx];
            }
        }
    }
}

// ---------------------------------------------------------------------------
extern "C" void kernel_launch(void* const* d_in, const int* in_sizes, int n_in,
                              void* d_out, int out_size, void* d_ws, size_t ws_size,
                              hipStream_t stream) {
    (void)in_sizes; (void)n_in; (void)out_size; (void)ws_size;
    const float* x      = (const float*)d_in[0];
    const float* tt     = (const float*)d_in[1];
    const float* ln_w   = (const float*)d_in[2];
    const float* ln_b   = (const float*)d_in[3];
    const float* down_w = (const float*)d_in[4];
    const float* down_b = (const float*)d_in[5];
    const float* ln1_w  = (const float*)d_in[6];
    const float* ln1_b  = (const float*)d_in[7];
    const float* down1_w= (const float*)d_in[8];
    const float* down1_b= (const float*)d_in[9];
    const float* dw_w   = (const float*)d_in[10];
    const float* dw_b   = (const float*)d_in[11];
    const float* pw_w   = (const float*)d_in[12];
    const float* pw_b   = (const float*)d_in[13];
    const float* m1w    = (const float*)d_in[14];
    const float* m1b    = (const float*)d_in[15];
    const float* m2w    = (const float*)d_in[16];
    const float* m2b    = (const float*)d_in[17];
    const float* basis  = (const float*)d_in[18];
    const float* up_w   = (const float*)d_in[19];
    const float* up_b   = (const float*)d_in[20];
    float* out = (float*)d_out;
    char* ws = (char*)d_ws;

    // workspace layout (bytes)
    __bf16* wln_down  = (__bf16*)(ws + 0);          // 96*768*2  = 147456
    __bf16* wln_down1 = (__bf16*)(ws + 147456);
    __bf16* wbf_up    = (__bf16*)(ws + 294912);     // 768*96*2
    __bf16* wbf_pw    = (__bf16*)(ws + 442368);     // 192*96*2 = 36864
    float*  part      = (float*)(ws + 479232);      // 8*96*4 = 3072
    float*  wts       = (float*)(ws + 482304);      // 32*4
    float*  swcb      = (float*)(ws + 482560);      // 2*192*4 = 1536
    __bf16* x_emb     = (__bf16*)(ws + 524288);     // 32768*96*2 = 6291456
    __bf16* t_emb     = (__bf16*)(ws + 6815744);
    __bf16* ybuf      = (__bf16*)(ws + 13107200);
    __bf16* common    = (__bf16*)(ws + 19398656);
    __bf16* convout   = (__bf16*)(ws + 25690112);

    // opt-in to >64KB dynamic LDS for k_downf (not a stream op; capture-safe)
    (void)hipFuncSetAttribute((const void*)k_downf,
                              hipFuncAttributeMaxDynamicSharedMemorySize, 147456);

    k_prep<<<141, 256, 0, stream>>>(down_w, down_b, ln_w, ln_b,
                                    down1_w, down1_b, ln1_w, ln1_b,
                                    wln_down, wln_down1, swcb,
                                    up_w, pw_w, wbf_up, wbf_pw, part);
    k_downf<<<256, 1024, 147456, stream>>>(x, tt, wln_down, wln_down1, swcb,
                                           x_emb, t_emb, part);
    k_mlp<<<8, 128, 0, stream>>>(part, m1w, m1b, m2w, m2b, wts);
    k_dwconv<<<512, 256, 0, stream>>>(t_emb, dw_w, dw_b, ybuf);
    k_style<<<512, 256, 0, stream>>>(ybuf, wbf_pw, pw_b, x_emb, common);
    k_circ<<<1024, 192, 0, stream>>>(common, wts, basis, convout);
    k_up<<<2048, 256, 0, stream>>>(convout, wbf_up, up_b, x, out);
}

// Round 8
// 177.714 us; speedup vs baseline: 1.4420x; 1.0009x over previous
//
#include <hip/hip_runtime.h>

#define DIM_ 768
#define MID_ 96

typedef float f32x4 __attribute__((ext_vector_type(4)));
typedef __bf16 bf16x8 __attribute__((ext_vector_type(8)));
typedef __bf16 bf16x4 __attribute__((ext_vector_type(4)));

// ---------------------------------------------------------------------------
// K_prep: fused weight prep.
// Blocks [0,48): fold LN into down/down1 weights (192 waves -> (mat,n)).
// Blocks [48,141): bf16-cast up_w, pw_w; zero gvec partials.
// ---------------------------------------------------------------------------
__global__ __launch_bounds__(256) void k_prep(
        const float* __restrict__ dw, const float* __restrict__ db,
        const float* __restrict__ lnw0, const float* __restrict__ lnb0,
        const float* __restrict__ d1w, const float* __restrict__ d1b,
        const float* __restrict__ lnw1, const float* __restrict__ lnb1,
        __bf16* __restrict__ wln0, __bf16* __restrict__ wln1,
        float* __restrict__ swcb,
        const float* __restrict__ uw, const float* __restrict__ pw,
        __bf16* __restrict__ bup, __bf16* __restrict__ bpw,
        float* __restrict__ part) {
    if (blockIdx.x >= 48) {
        const int t = (blockIdx.x - 48) * 256 + threadIdx.x;
        const float* src;
        __bf16* dst;
        int i;
        if (t < 18432)      { src = uw; dst = bup; i = t; }
        else if (t < 23040) { src = pw; dst = bpw; i = t - 18432; }
        else if (t < 23808) { part[t - 23040] = 0.f; return; }
        else return;
        float4 v = reinterpret_cast<const float4*>(src)[i];
        bf16x4 o;
        o[0] = (__bf16)v.x; o[1] = (__bf16)v.y;
        o[2] = (__bf16)v.z; o[3] = (__bf16)v.w;
        *reinterpret_cast<bf16x4*>(dst + (size_t)i * 4) = o;
        return;
    }
    const int wid = blockIdx.x * 4 + (threadIdx.x >> 6);
    const int lane = threadIdx.x & 63;
    const int mat = wid >= 96;
    const int n = mat ? wid - 96 : wid;
    const float* W   = mat ? d1w : dw;
    const float* bia = mat ? d1b : db;
    const float* lw  = mat ? lnw1 : lnw0;
    const float* lb  = mat ? lnb1 : lnb0;
    __bf16* dst = mat ? wln1 : wln0;
    float sacc = 0.f, cacc = 0.f;
#pragma unroll
    for (int j = 0; j < 12; ++j) {
        const int k = j * 64 + lane;
        const float w = W[(size_t)n * DIM_ + k];
        const float val = w * lw[k];
        const __bf16 bv = (__bf16)val;
        dst[(size_t)n * DIM_ + k] = bv;
        sacc += (float)bv;
        cacc += lb[k] * w;
    }
#pragma unroll
    for (int m = 1; m < 64; m <<= 1) {
        sacc += __shfl_xor(sacc, m, 64);
        cacc += __shfl_xor(cacc, m, 64);
    }
    if (lane == 0) {
        swcb[mat * 192 + n] = sacc;               // sw
        swcb[mat * 192 + 96 + n] = cacc + bia[n]; // cb
    }
}

// ---------------------------------------------------------------------------
// K_downf: fused LN+GEMM for BOTH x and t in one dispatch.
// Grid 256: blocks [0,128) -> x, [128,256) -> t. Block: 1024 thr (16 waves),
// 256 rows; each wave owns 16 distinct rows x full N=96 (6 frags).
// W (96x768 bf16 = 147 KB) LDS-resident in fragment order (conflict-free).
// Pipeline kept in bf16 to FIT 64 VGPRs (r6/r7: fp32 depth-4 = spills):
//   raw fp32 stages for kt+2,kt+3 (16 VGPR) + ready bf16 frags kt,kt+1 (8)
//   + acc (24) + temps ~= 60 <= 64. Stats folded into the convert step.
// LN algebraic: out = acc*rstd - mu*rstd*sw + cb (weights pre-folded).
// ---------------------------------------------------------------------------
__global__ __launch_bounds__(1024)
__attribute__((amdgpu_waves_per_eu(4, 4)))
void k_downf(
        const float* __restrict__ xsrc, const float* __restrict__ tsrc,
        const __bf16* __restrict__ wln0, const __bf16* __restrict__ wln1,
        const float* __restrict__ swcb, __bf16* __restrict__ xemb,
        __bf16* __restrict__ temb, float* __restrict__ part) {
    extern __shared__ __bf16 Wp[];   // 96*768 = 73728 elems = 147456 B
    const int t = threadIdx.x;
    const int half = blockIdx.x >> 7;      // 0: x, 1: t
    const int mb = blockIdx.x & 127;
    const float* src = half ? tsrc : xsrc;
    const __bf16* wln = half ? wln1 : wln0;
    const float* sc = swcb + half * 192;
    __bf16* outb = half ? temb : xemb;

    // stage W in fragment order: idx = (kt*6 + f)*64 + lane
#pragma unroll
    for (int i = 0; i < 9; ++i) {
        const int idx = t + i * 1024;          // 0..9215
        const int ls = idx & 63;
        const int rem = idx >> 6;              // kt*6 + f
        const int kt = rem / 6;
        const int f = rem - kt * 6;
        const int row = f * 16 + (ls & 15);
        const int col = kt * 32 + (ls >> 4) * 8;
        *reinterpret_cast<bf16x8*>(Wp + (size_t)idx * 8) =
            *reinterpret_cast<const bf16x8*>(wln + (size_t)row * DIM_ + col);
    }
    __syncthreads();

    const int lane = t & 63, wave = t >> 6;   // 16 waves
    const int l15 = lane & 15, l4 = lane >> 4;
    const int row = mb * 256 + wave * 16 + l15;
    const float* rp = src + (size_t)row * DIM_ + l4 * 8;

    float s = 0.f, sq = 0.f;
    f32x4 acc[6] = {};

    // convert + stats: fp32 pair -> bf16 fragment
    auto cvt = [&](const float4& v0, const float4& v1) -> bf16x8 {
        s += v0.x + v0.y + v0.z + v0.w + v1.x + v1.y + v1.z + v1.w;
        sq += v0.x * v0.x + v0.y * v0.y + v0.z * v0.z + v0.w * v0.w +
              v1.x * v1.x + v1.y * v1.y + v1.z * v1.z + v1.w * v1.w;
        bf16x8 a;
        a[0] = (__bf16)v0.x; a[1] = (__bf16)v0.y;
        a[2] = (__bf16)v0.z; a[3] = (__bf16)v0.w;
        a[4] = (__bf16)v1.x; a[5] = (__bf16)v1.y;
        a[6] = (__bf16)v1.z; a[7] = (__bf16)v1.w;
        return a;
    };
    auto consume = [&](const bf16x8& a, int kt) {
        const __bf16* bp = Wp + ((size_t)(kt * 6) * 64 + lane) * 8;
#pragma unroll
        for (int f = 0; f < 6; ++f) {
            bf16x8 b = *reinterpret_cast<const bf16x8*>(bp + (size_t)f * 64 * 8);
            acc[f] = __builtin_amdgcn_mfma_f32_16x16x32_bf16(a, b, acc[f], 0, 0, 0);
        }
    };

    // prologue: frags for kt=0,1 ready; raw loads for kt=2,3 in flight
    float4 w0a = *reinterpret_cast<const float4*>(rp + 0);
    float4 w0b = *reinterpret_cast<const float4*>(rp + 4);
    float4 w1a = *reinterpret_cast<const float4*>(rp + 32);
    float4 w1b = *reinterpret_cast<const float4*>(rp + 36);
    bf16x8 a0 = cvt(w0a, w0b);
    bf16x8 a1 = cvt(w1a, w1b);
    w0a = *reinterpret_cast<const float4*>(rp + 64);
    w0b = *reinterpret_cast<const float4*>(rp + 68);
    w1a = *reinterpret_cast<const float4*>(rp + 96);
    w1b = *reinterpret_cast<const float4*>(rp + 100);

#pragma unroll
    for (int kt = 0; kt < 24; kt += 2) {
        // step A: consume kt; promote raw kt+2 -> frag; issue load kt+4
        consume(a0, kt);
        if (kt + 2 < 24) {
            a0 = cvt(w0a, w0b);
            if (kt + 4 < 24) {
                w0a = *reinterpret_cast<const float4*>(rp + (kt + 4) * 32);
                w0b = *reinterpret_cast<const float4*>(rp + (kt + 4) * 32 + 4);
            }
        }
        // step B: consume kt+1; promote raw kt+3; issue load kt+5
        consume(a1, kt + 1);
        if (kt + 3 < 24) {
            a1 = cvt(w1a, w1b);
            if (kt + 5 < 24) {
                w1a = *reinterpret_cast<const float4*>(rp + (kt + 5) * 32);
                w1b = *reinterpret_cast<const float4*>(rp + (kt + 5) * 32 + 4);
            }
        }
    }

    // finish stats: combine the 4 k-quarter lanes of each row
    s += __shfl_xor(s, 16, 64); sq += __shfl_xor(sq, 16, 64);
    s += __shfl_xor(s, 32, 64); sq += __shfl_xor(sq, 32, 64);
    const float mean = s * (1.f / 768.f);
    const float rstd = rsqrtf(sq * (1.f / 768.f) - mean * mean + 1e-6f);
    const float mur = mean * rstd;
    float rstd_r[4], mur_r[4];
#pragma unroll
    for (int rr = 0; rr < 4; ++rr) {
        rstd_r[rr] = __shfl(rstd, l4 * 4 + rr, 64);
        mur_r[rr]  = __shfl(mur,  l4 * 4 + rr, 64);
    }

    const int orow0 = mb * 256 + wave * 16 + l4 * 4;
    const int batch = mb >> 4;     // 16 blocks per image
#pragma unroll
    for (int f = 0; f < 6; ++f) {
        const int col = f * 16 + l15;
        const float swc = sc[col];
        const float cbc = sc[96 + col];
        float colsum = 0.f;
#pragma unroll
        for (int rr = 0; rr < 4; ++rr) {
            const float val = acc[f][rr] * rstd_r[rr] - mur_r[rr] * swc + cbc;
            outb[(size_t)(orow0 + rr) * MID_ + col] = (__bf16)val;
            colsum += val;
        }
        if (half == 0) {
            colsum += __shfl_xor(colsum, 16, 64);
            colsum += __shfl_xor(colsum, 32, 64);
            if (l4 == 0) atomicAdd(&part[batch * MID_ + col], colsum);
        }
    }
}

// ---------------------------------------------------------------------------
// K_mlp: gvec mean from part, MLP (96->24 relu ->4), softmax -> wts [8,4]
// ---------------------------------------------------------------------------
__global__ __launch_bounds__(128) void k_mlp(const float* __restrict__ part,
        const float* __restrict__ m1w, const float* __restrict__ m1b,
        const float* __restrict__ m2w, const float* __restrict__ m2b,
        float* __restrict__ wts) {
    const int b = blockIdx.x, t = threadIdx.x;
    __shared__ float gv[96];
    __shared__ float hid[24];
    __shared__ float lg[4];
    if (t < 96) gv[t] = part[b * MID_ + t] * (1.f / 4096.f);
    __syncthreads();
    if (t < 24) {
        float s = m1b[t];
        for (int c = 0; c < 96; ++c) s += gv[c] * m1w[t * 96 + c];
        hid[t] = fmaxf(s, 0.f);
    }
    __syncthreads();
    if (t < 4) {
        float s = m2b[t];
        for (int j = 0; j < 24; ++j) s += hid[j] * m2w[t * 24 + j];
        lg[t] = s;
    }
    __syncthreads();
    if (t < 4) {
        const float m = fmaxf(fmaxf(lg[0], lg[1]), fmaxf(lg[2], lg[3]));
        const float e = __expf(lg[t] - m);
        const float sum = __expf(lg[0] - m) + __expf(lg[1] - m) +
                          __expf(lg[2] - m) + __expf(lg[3] - m);
        wts[b * 4 + t] = e / sum;
    }
}

// ---------------------------------------------------------------------------
// K_dwconv: depthwise 3x3 conv (zero pad) + SiLU. temb bf16 -> y bf16.
// ---------------------------------------------------------------------------
__global__ __launch_bounds__(256) void k_dwconv(const __bf16* __restrict__ temb,
        const float* __restrict__ dww, const float* __restrict__ dwb,
        __bf16* __restrict__ y) {
    __shared__ float wls[96 * 9];
    __shared__ float bls[96];
    const int t = threadIdx.x;
    for (int i = t; i < 96 * 9; i += 256) wls[i] = dww[i];
    if (t < 96) bls[t] = dwb[t];
    __syncthreads();
    const int b = blockIdx.x >> 6, h = blockIdx.x & 63;
    const __bf16* base = temb + (size_t)b * 4096 * MID_;
    for (int o = t; o < 64 * 96; o += 256) {
        const int w = o / 96;
        const int c = o - w * 96;
        float acc = bls[c];
#pragma unroll
        for (int dh = 0; dh < 3; ++dh) {
            const int hh = h + dh - 1;
            if (hh < 0 || hh > 63) continue;
#pragma unroll
            for (int dw = 0; dw < 3; ++dw) {
                const int ww = w + dw - 1;
                if (ww < 0 || ww > 63) continue;
                acc += (float)base[((size_t)hh * 64 + ww) * MID_ + c] *
                       wls[c * 9 + dh * 3 + dw];
            }
        }
        y[((size_t)(b * 64 + h) * 64 + w) * MID_ + c] =
            (__bf16)(acc / (1.f + __expf(-acc)));
    }
}

// ---------------------------------------------------------------------------
// K_style: style GEMM (y @ pw_w^T + pw_b) fused with modulation:
// common = x_emb * (1 + gamma) + beta -> bf16. K=96 fully staged, 1 barrier.
// ---------------------------------------------------------------------------
__global__ __launch_bounds__(256) void k_style(const __bf16* __restrict__ y,
        const __bf16* __restrict__ wpw, const float* __restrict__ pwb,
        const __bf16* __restrict__ xemb, __bf16* __restrict__ common) {
    __shared__ bf16x8 As[64][13];
    __shared__ bf16x8 Bs[192][13];
    const int t = threadIdx.x;
    const int row0 = blockIdx.x * 64;
    for (int idx = t; idx < 768; idx += 256) {
        const int rr = idx / 12, q = idx - rr * 12;
        As[rr][q] = *reinterpret_cast<const bf16x8*>(
            y + (size_t)(row0 + rr) * MID_ + q * 8);
    }
    for (int idx = t; idx < 2304; idx += 256) {
        const int rr = idx / 12, q = idx - rr * 12;
        Bs[rr][q] = *reinterpret_cast<const bf16x8*>(
            wpw + (size_t)rr * MID_ + q * 8);
    }
    __syncthreads();
    const int lane = t & 63, wave = t >> 6;
    const int l15 = lane & 15, l4 = lane >> 4;
    f32x4 acc[12] = {};
    const int ar = wave * 16 + l15;
#pragma unroll
    for (int kt = 0; kt < 3; ++kt) {
        bf16x8 a = As[ar][kt * 4 + l4];
#pragma unroll
        for (int f = 0; f < 12; ++f) {
            bf16x8 b = Bs[f * 16 + l15][kt * 4 + l4];
            acc[f] = __builtin_amdgcn_mfma_f32_16x16x32_bf16(a, b, acc[f], 0, 0, 0);
        }
    }
    const int orow = row0 + wave * 16 + l4 * 4;
#pragma unroll
    for (int f = 0; f < 6; ++f) {
        const int col = f * 16 + l15;
        const float pbg = pwb[col];
        const float pbb = pwb[col + 96];
#pragma unroll
        for (int rr = 0; rr < 4; ++rr) {
            const float g = acc[f][rr] + pbg;
            const float bt = acc[f + 6][rr] + pbb;
            const float xe = (float)xemb[(size_t)(orow + rr) * MID_ + col];
            common[(size_t)(orow + rr) * MID_ + col] = (__bf16)(xe * (1.f + g) + bt);
        }
    }
}

// ---------------------------------------------------------------------------
// K_circ: circular 7x7 conv (== rfft2/irfft2 product). dyn built in LDS.
// ---------------------------------------------------------------------------
__global__ __launch_bounds__(192) void k_circ(const __bf16* __restrict__ common,
        const float* __restrict__ wts, const float* __restrict__ basis,
        __bf16* __restrict__ outc) {
    __shared__ float dyn[49][96];
    const int t = threadIdx.x;
    const int b = blockIdx.x >> 7;
    const int h = (blockIdx.x >> 1) & 63;
    const int wslice = blockIdx.x & 1;
    const float w0 = wts[b * 4 + 0], w1 = wts[b * 4 + 1];
    const float w2 = wts[b * 4 + 2], w3 = wts[b * 4 + 3];
    for (int idx = t; idx < 4704; idx += 192) {
        const int c = idx / 49;
        const int pq = idx - c * 49;
        const size_t off = (size_t)c * 49 + pq;
        dyn[pq][c] = w0 * basis[off] + w1 * basis[off + 4704] +
                     w2 * basis[off + 9408] + w3 * basis[off + 14112];
    }
    __syncthreads();
    const int c = t % 96;
    const int wg = t / 96;
    const int wbase = wslice * 32 + wg * 16;
    const __bf16* cb = common + (size_t)b * 4096 * MID_ + c;
    float acc[16] = {};
#pragma unroll 1
    for (int p = 0; p < 7; ++p) {
        const int hh = (h + 3 - p) & 63;
        const __bf16* rp = cb + (size_t)hh * 64 * MID_;
        float dynr[7];
#pragma unroll
        for (int q = 0; q < 7; ++q) dynr[q] = dyn[p * 7 + q][c];
#pragma unroll
        for (int i = 0; i < 22; ++i) {
            const int ww = (wbase - 3 + i) & 63;
            const float cm = (float)rp[(size_t)ww * MID_];
#pragma unroll
            for (int q = 0; q < 7; ++q) {
                const int li = i + q - 6;
                if (li >= 0 && li < 16) acc[li] += dynr[q] * cm;
            }
        }
    }
    const size_t obase = ((size_t)(b * 64 + h) * 64 + wbase) * MID_ + c;
#pragma unroll
    for (int li = 0; li < 16; ++li)
        outc[obase + (size_t)li * MID_] = (__bf16)acc[li];
}

// ---------------------------------------------------------------------------
// K_up: out = a_in[32768,96] @ up_w_bf16[768,96]^T + up_b + x  (fp32 out)
// ---------------------------------------------------------------------------
__global__ __launch_bounds__(256) void k_up(const __bf16* __restrict__ a_in,
        const __bf16* __restrict__ wbf, const float* __restrict__ upb,
        const float* __restrict__ x, float* __restrict__ out) {
    __shared__ bf16x8 As[128][13];
    __shared__ bf16x8 Ws[96][13];
    const int t = threadIdx.x;
    const int mt = blockIdx.x >> 3, nt = blockIdx.x & 7;
    const int row0 = mt * 128, col0 = nt * 96;
    for (int idx = t; idx < 1536; idx += 256) {
        const int rr = idx / 12, q = idx - rr * 12;
        As[rr][q] = *reinterpret_cast<const bf16x8*>(
            a_in + (size_t)(row0 + rr) * MID_ + q * 8);
    }
    for (int idx = t; idx < 1152; idx += 256) {
        const int rr = idx / 12, q = idx - rr * 12;
        Ws[rr][q] = *reinterpret_cast<const bf16x8*>(
            wbf + (size_t)(col0 + rr) * MID_ + q * 8);
    }
    __syncthreads();
    const int lane = t & 63, wave = t >> 6;
    const int l15 = lane & 15, l4 = lane >> 4;
    f32x4 acc[2][6] = {};
#pragma unroll
    for (int kt = 0; kt < 3; ++kt) {
        bf16x8 a0 = As[wave * 32 + l15][kt * 4 + l4];
        bf16x8 a1 = As[wave * 32 + 16 + l15][kt * 4 + l4];
#pragma unroll
        for (int f = 0; f < 6; ++f) {
            bf16x8 b = Ws[f * 16 + l15][kt * 4 + l4];
            acc[0][f] = __builtin_amdgcn_mfma_f32_16x16x32_bf16(a0, b, acc[0][f], 0, 0, 0);
            acc[1][f] = __builtin_amdgcn_mfma_f32_16x16x32_bf16(a1, b, acc[1][f], 0, 0, 0);
        }
    }
#pragma unroll
    for (int mr = 0; mr < 2; ++mr) {
        const int orow = row0 + wave * 32 + mr * 16 + l4 * 4;
#pragma unroll
        for (int f = 0; f < 6; ++f) {
            const int col = col0 + f * 16 + l15;
            const float ub = upb[col];
#pragma unroll
            for (int rr = 0; rr < 4; ++rr) {
                const size_t idx = (size_t)(orow + rr) * DIM_ + col;
                out[idx] = acc[mr][f][rr] + ub + x[idx];
            }
        }
    }
}

// ---------------------------------------------------------------------------
extern "C" void kernel_launch(void* const* d_in, const int* in_sizes, int n_in,
                              void* d_out, int out_size, void* d_ws, size_t ws_size,
                              hipStream_t stream) {
    (void)in_sizes; (void)n_in; (void)out_size; (void)ws_size;
    const float* x      = (const float*)d_in[0];
    const float* tt     = (const float*)d_in[1];
    const float* ln_w   = (const float*)d_in[2];
    const float* ln_b   = (const float*)d_in[3];
    const float* down_w = (const float*)d_in[4];
    const float* down_b = (const float*)d_in[5];
    const float* ln1_w  = (const float*)d_in[6];
    const float* ln1_b  = (const float*)d_in[7];
    const float* down1_w= (const float*)d_in[8];
    const float* down1_b= (const float*)d_in[9];
    const float* dw_w   = (const float*)d_in[10];
    const float* dw_b   = (const float*)d_in[11];
    const float* pw_w   = (const float*)d_in[12];
    const float* pw_b   = (const float*)d_in[13];
    const float* m1w    = (const float*)d_in[14];
    const float* m1b    = (const float*)d_in[15];
    const float* m2w    = (const float*)d_in[16];
    const float* m2b    = (const float*)d_in[17];
    const float* basis  = (const float*)d_in[18];
    const float* up_w   = (const float*)d_in[19];
    const float* up_b   = (const float*)d_in[20];
    float* out = (float*)d_out;
    char* ws = (char*)d_ws;

    // workspace layout (bytes)
    __bf16* wln_down  = (__bf16*)(ws + 0);          // 96*768*2  = 147456
    __bf16* wln_down1 = (__bf16*)(ws + 147456);
    __bf16* wbf_up    = (__bf16*)(ws + 294912);     // 768*96*2
    __bf16* wbf_pw    = (__bf16*)(ws + 442368);     // 192*96*2 = 36864
    float*  part      = (float*)(ws + 479232);      // 8*96*4 = 3072
    float*  wts       = (float*)(ws + 482304);      // 32*4
    float*  swcb      = (float*)(ws + 482560);      // 2*192*4 = 1536
    __bf16* x_emb     = (__bf16*)(ws + 524288);     // 32768*96*2 = 6291456
    __bf16* t_emb     = (__bf16*)(ws + 6815744);
    __bf16* ybuf      = (__bf16*)(ws + 13107200);
    __bf16* common    = (__bf16*)(ws + 19398656);
    __bf16* convout   = (__bf16*)(ws + 25690112);

    // opt-in to >64KB dynamic LDS for k_downf (not a stream op; capture-safe)
    (void)hipFuncSetAttribute((const void*)k_downf,
                              hipFuncAttributeMaxDynamicSharedMemorySize, 147456);

    k_prep<<<141, 256, 0, stream>>>(down_w, down_b, ln_w, ln_b,
                                    down1_w, down1_b, ln1_w, ln1_b,
                                    wln_down, wln_down1, swcb,
                                    up_w, pw_w, wbf_up, wbf_pw, part);
    k_downf<<<256, 1024, 147456, stream>>>(x, tt, wln_down, wln_down1, swcb,
                                           x_emb, t_emb, part);
    k_mlp<<<8, 128, 0, stream>>>(part, m1w, m1b, m2w, m2b, wts);
    k_dwconv<<<512, 256, 0, stream>>>(t_emb, dw_w, dw_b, ybuf);
    k_style<<<512, 256, 0, stream>>>(ybuf, wbf_pw, pw_b, x_emb, common);
    k_circ<<<1024, 192, 0, stream>>>(common, wts, basis, convout);
    k_up<<<2048, 256, 0, stream>>>(convout, wbf_up, up_b, x, out);
}